// Round 3
// baseline (534.217 us; speedup 1.0000x reference)
//
#include <hip/hip_runtime.h>
#include <math.h>

// Shapes (fixed by the problem)
#define B_  32
#define T_  768
#define C_  448
#define E_  256
#define N_  3136   // 56*56
#define N4_ 784    // N_/4 (float4 per image row)
#define NTILE_ 16  // n-tiles per batch
#define NT4_ 49    // float4 per tile (196 floats); 16*196 = 3136
#define TOTAL4_ 11239424  // B_*C_*N_/4

// ---------------- Kernel A: q = text@q_w^T + q_b ; qk = scale * k_w^T q ----
__global__ __launch_bounds__(256) void kA_qk(
    const float* __restrict__ text, const float* __restrict__ q_w,
    const float* __restrict__ q_b,  const float* __restrict__ k_w,
    float* __restrict__ qk)
{
    const int b = blockIdx.x, tid = threadIdx.x;
    __shared__ float t_lds[T_];
    __shared__ float q_lds[E_];
    for (int i = tid; i < T_; i += 256) t_lds[i] = text[b * T_ + i];
    __syncthreads();
    {   // each thread computes one q[e]
        const int e = tid;
        float acc = q_b[e];
        const float* qw = q_w + (size_t)e * T_;
        #pragma unroll 8
        for (int t = 0; t < T_; ++t) acc = fmaf(t_lds[t], qw[t], acc);
        q_lds[e] = acc;
    }
    __syncthreads();
    const float scale = 0.0625f;  // 1/sqrt(E_)
    for (int c = tid; c < C_; c += 256) {
        float acc = 0.f;
        #pragma unroll 4
        for (int e = 0; e < E_; ++e) acc = fmaf(q_lds[e], k_w[e * C_ + c], acc);
        qk[b * C_ + c] = acc * scale;
    }
}

// ---------------- Kernel B: fused logits + local softmax + local pool ------
// Block = (tile t, batch b). Tile covers n in [t*196, (t+1)*196).
// Pass 1: logit[n] = sum_c qk[b,c]*img[b,c,n]   (c split across 4 waves)
// Local softmax stats (mloc, sloc); weights w[n] = exp(l[n]-mloc) in LDS.
// Pass 2: Ppart[b,t,c] = sum_{n in tile} w[n]*img[b,c,n]  (tile is L2/L3-hot)
__global__ __launch_bounds__(256) void kB_logits_pool(
    const float* __restrict__ img, const float* __restrict__ qk,
    float* __restrict__ Ppart,   // [B_][NTILE_][C_]
    float* __restrict__ msloc)   // [B_][NTILE_][2]  (mloc, sloc)
{
    const int t = blockIdx.x;          // 0..15
    const int b = blockIdx.y;          // 0..31
    const int tid = threadIdx.x;
    const int w = tid >> 6, lane = tid & 63;

    __shared__ float  qk_lds[C_];
    __shared__ float4 plog[4][NT4_];
    __shared__ float4 w_lds[NT4_];

    for (int c = tid; c < C_; c += 256) qk_lds[c] = qk[b * C_ + c];
    __syncthreads();

    const float4* imgb = (const float4*)img + (size_t)(b * C_) * N4_ + t * NT4_;

    // ---- pass 1: partial logits; wave w covers c in [w*112, w*112+112)
    const int c0 = w * 112;
    if (lane < NT4_) {
        float4 acc = {0.f, 0.f, 0.f, 0.f};
        #pragma unroll 4
        for (int k = 0; k < 112; ++k) {
            const float qkc = qk_lds[c0 + k];
            const float4 x = imgb[(size_t)(c0 + k) * N4_ + lane];
            acc.x = fmaf(qkc, x.x, acc.x); acc.y = fmaf(qkc, x.y, acc.y);
            acc.z = fmaf(qkc, x.z, acc.z); acc.w = fmaf(qkc, x.w, acc.w);
        }
        plog[w][lane] = acc;
    }
    __syncthreads();

    // ---- local softmax (wave 0 only)
    if (w == 0) {
        float4 l4;
        float m = -1e30f;
        if (lane < NT4_) {
            l4 = plog[0][lane];
            const float4 p1 = plog[1][lane], p2 = plog[2][lane], p3 = plog[3][lane];
            l4.x += p1.x + p2.x + p3.x; l4.y += p1.y + p2.y + p3.y;
            l4.z += p1.z + p2.z + p3.z; l4.w += p1.w + p2.w + p3.w;
            m = fmaxf(fmaxf(l4.x, l4.y), fmaxf(l4.z, l4.w));
        }
        for (int off = 32; off; off >>= 1) m = fmaxf(m, __shfl_xor(m, off));
        float s = 0.f;
        if (lane < NT4_) {
            float4 e4;
            e4.x = expf(l4.x - m); e4.y = expf(l4.y - m);
            e4.z = expf(l4.z - m); e4.w = expf(l4.w - m);
            w_lds[lane] = e4;
            s = e4.x + e4.y + e4.z + e4.w;
        }
        for (int off = 32; off; off >>= 1) s += __shfl_xor(s, off);
        if (lane == 0) {
            msloc[(b * NTILE_ + t) * 2 + 0] = m;
            msloc[(b * NTILE_ + t) * 2 + 1] = s;
        }
    }
    __syncthreads();

    // ---- pass 2: per-tile weighted channel sums (re-read tile, L2/L3-hot)
    #pragma unroll 2
    for (int k = 0; k < 112; ++k) {
        const int c = c0 + k;
        float p = 0.f;
        if (lane < NT4_) {
            const float4 x  = imgb[(size_t)c * N4_ + lane];
            const float4 ww = w_lds[lane];
            p = ww.x * x.x + ww.y * x.y + ww.z * x.z + ww.w * x.w;
        }
        for (int off = 32; off; off >>= 1) p += __shfl_xor(p, off);
        if (lane == 0) Ppart[((size_t)b * NTILE_ + t) * C_ + c] = p;
    }
}

// ---------------- Kernel C: combine tiles + v GEMV + o GEMV ----------------
__global__ __launch_bounds__(256) void kC_combine(
    const float* __restrict__ Ppart, const float* __restrict__ msloc,
    const float* __restrict__ v_w,   const float* __restrict__ v_b,
    const float* __restrict__ o_w,   const float* __restrict__ o_b,
    float* __restrict__ outvec)
{
    const int b = blockIdx.x, tid = threadIdx.x;
    __shared__ float p_lds[C_];
    __shared__ float e_lds[E_];
    __shared__ float scl[NTILE_];
    __shared__ float invD_sh;

    if (tid == 0) {
        float M = -1e30f;
        for (int t = 0; t < NTILE_; ++t)
            M = fmaxf(M, msloc[(b * NTILE_ + t) * 2]);
        float D = 0.f;
        for (int t = 0; t < NTILE_; ++t) {
            const float e = expf(msloc[(b * NTILE_ + t) * 2] - M);
            scl[t] = e;
            D = fmaf(msloc[(b * NTILE_ + t) * 2 + 1], e, D);
        }
        invD_sh = 1.f / D;
    }
    __syncthreads();
    const float invD = invD_sh;

    for (int c = tid; c < C_; c += 256) {
        float s = 0.f;
        #pragma unroll
        for (int t = 0; t < NTILE_; ++t)
            s = fmaf(Ppart[((size_t)b * NTILE_ + t) * C_ + c], scl[t], s);
        p_lds[c] = s * invD;   // pooled_img[b,c] = sum_n attn*img
    }
    __syncthreads();
    {   // pooled[e] = v_b[e] + v_w[e,:] . pooled_img
        const int e = tid;
        float acc = v_b[e];
        const float* vw = v_w + (size_t)e * C_;
        #pragma unroll 4
        for (int c = 0; c < C_; ++c) acc = fmaf(vw[c], p_lds[c], acc);
        e_lds[e] = acc;
    }
    __syncthreads();
    for (int c = tid; c < C_; c += 256) {
        float acc = o_b[c];
        const float* ow = o_w + (size_t)c * E_;
        #pragma unroll 4
        for (int e = 0; e < E_; ++e) acc = fmaf(ow[e], e_lds[e], acc);
        outvec[b * C_ + c] = acc;
    }
}

// ---------------- Kernel D: out = img + outvec[b,c] broadcast --------------
__global__ __launch_bounds__(256) void kD_add(
    const float* __restrict__ img, const float* __restrict__ outvec,
    float* __restrict__ out)
{
    const unsigned i = blockIdx.x * 256u + threadIdx.x;   // < TOTAL4_
    const float4 x = ((const float4*)img)[i];
    const float o = outvec[i / N4_];   // row = b*C_+c; L1/L2 broadcast
    float4 r;
    r.x = x.x + o; r.y = x.y + o; r.z = x.z + o; r.w = x.w + o;
    ((float4*)out)[i] = r;
}

extern "C" void kernel_launch(void* const* d_in, const int* in_sizes, int n_in,
                              void* d_out, int out_size, void* d_ws, size_t ws_size,
                              hipStream_t stream) {
    const float* text = (const float*)d_in[0];
    const float* img  = (const float*)d_in[1];
    const float* q_w  = (const float*)d_in[2];
    const float* q_b  = (const float*)d_in[3];
    const float* k_w  = (const float*)d_in[4];
    const float* k_b  = (const float*)d_in[5];  // unused: cancels in softmax
    const float* v_w  = (const float*)d_in[6];
    const float* v_b  = (const float*)d_in[7];
    const float* o_w  = (const float*)d_in[8];
    const float* o_b  = (const float*)d_in[9];
    float* out = (float*)d_out;
    (void)k_b; (void)in_sizes; (void)n_in; (void)out_size; (void)ws_size;

    // workspace layout (floats)
    float* ws     = (float*)d_ws;
    float* qk     = ws;                         // B_*C_            = 14336
    float* Ppart  = qk + B_ * C_;               // B_*NTILE_*C_     = 229376
    float* msloc  = Ppart + B_ * NTILE_ * C_;   // B_*NTILE_*2      = 1024
    float* outvec = msloc + B_ * NTILE_ * 2;    // B_*C_            = 14336

    kA_qk<<<B_, 256, 0, stream>>>(text, q_w, q_b, k_w, qk);
    kB_logits_pool<<<dim3(NTILE_, B_), 256, 0, stream>>>(img, qk, Ppart, msloc);
    kC_combine<<<B_, 256, 0, stream>>>(Ppart, msloc, v_w, v_b, o_w, o_b, outvec);
    kD_add<<<TOTAL4_ / 256, 256, 0, stream>>>(img, outvec, out);
}

// Round 4
// 503.175 us; speedup vs baseline: 1.0617x; 1.0617x over previous
//
#include <hip/hip_runtime.h>
#include <math.h>

// Shapes (fixed by the problem)
#define B_  32
#define T_  768
#define C_  448
#define E_  256
#define N_  3136   // 56*56
#define N4_ 784    // N_/4 (float4 per image row)
#define NT_ 49     // n-tiles per batch; tile = 64 floats = 16 float4
#define TOTAL4_ 11239424  // B_*C_*N_/4

// ---------------- Kernel A: q = text@q_w^T + q_b ; qk = scale * k_w^T q ----
__global__ __launch_bounds__(256) void kA_qk(
    const float* __restrict__ text, const float* __restrict__ q_w,
    const float* __restrict__ q_b,  const float* __restrict__ k_w,
    float* __restrict__ qk)
{
    const int b = blockIdx.x, tid = threadIdx.x;
    __shared__ float t_lds[T_];
    __shared__ float q_lds[E_];
    for (int i = tid; i < T_; i += 256) t_lds[i] = text[b * T_ + i];
    __syncthreads();
    {   // each thread computes one q[e]
        const int e = tid;
        float acc = q_b[e];
        const float* qw = q_w + (size_t)e * T_;
        #pragma unroll 8
        for (int t = 0; t < T_; ++t) acc = fmaf(t_lds[t], qw[t], acc);
        q_lds[e] = acc;
    }
    __syncthreads();
    const float scale = 0.0625f;  // 1/sqrt(E_)
    for (int c = tid; c < C_; c += 256) {
        float acc = 0.f;
        #pragma unroll 4
        for (int e = 0; e < E_; ++e) acc = fmaf(q_lds[e], k_w[e * C_ + c], acc);
        qk[b * C_ + c] = acc * scale;
    }
}

// ---------------- Kernel B: fused logits + local softmax + local pool ------
// Block = (n-tile nt, batch b); tile covers n in [nt*64, nt*64+64).
// Thread t = (cg = t>>4, n4 = t&15): handles channels c = 16i+cg, float4 n4.
// Pass 1: per-thread partial logits -> LDS -> wave0 softmax over 64 logits.
// Pass 2: re-read tile (L3-hot), 16-lane shfl reduce -> Ppart[b][nt][c].
__global__ __launch_bounds__(256) void kB_logits_pool(
    const float* __restrict__ img, const float* __restrict__ qk,
    float* __restrict__ Ppart,   // [B_][NT_][C_]
    float* __restrict__ msloc)   // [B_][NT_][2]  (mloc, sloc)
{
    const int nt = blockIdx.x;         // 0..48
    const int b  = blockIdx.y;         // 0..31
    const int tid = threadIdx.x;
    const int cg  = tid >> 4;          // 0..15 channel group
    const int n4  = tid & 15;          // 0..15 float4 within tile

    __shared__ float qk_lds[C_];
    __shared__ float partf[16 * 64];   // [cg][n] partial logits, 4 KB
    __shared__ float w_lds[64];        // exp weights for the 64 n's

    for (int c = tid; c < C_; c += 256) qk_lds[c] = qk[b * C_ + c];
    __syncthreads();

    const float4* imgb = (const float4*)img + (size_t)(b * C_) * N4_ + nt * 16;

    // ---- pass 1: partial logits
    float4 acc = {0.f, 0.f, 0.f, 0.f};
    #pragma unroll 4
    for (int i = 0; i < 28; ++i) {
        const int c = i * 16 + cg;
        const float w = qk_lds[c];
        const float4 x = imgb[(size_t)c * N4_ + n4];
        acc.x = fmaf(w, x.x, acc.x); acc.y = fmaf(w, x.y, acc.y);
        acc.z = fmaf(w, x.z, acc.z); acc.w = fmaf(w, x.w, acc.w);
    }
    ((float4*)partf)[cg * 16 + n4] = acc;
    __syncthreads();

    // ---- wave 0: reduce across 16 channel-groups, softmax over 64 logits
    if (tid < 64) {
        const int n = tid;
        float l = 0.f;
        #pragma unroll
        for (int g = 0; g < 16; ++g) l += partf[g * 64 + n];
        float m = l;
        for (int off = 32; off; off >>= 1) m = fmaxf(m, __shfl_xor(m, off));
        const float e = expf(l - m);
        float s = e;
        for (int off = 32; off; off >>= 1) s += __shfl_xor(s, off);
        w_lds[n] = e;
        if (n == 0) {
            msloc[(b * NT_ + nt) * 2 + 0] = m;
            msloc[(b * NT_ + nt) * 2 + 1] = s;
        }
    }
    __syncthreads();

    // ---- pass 2: weighted channel sums over the tile (cache-hot re-read)
    const float4 w4 = ((const float4*)w_lds)[n4];
    #pragma unroll 4
    for (int i = 0; i < 28; ++i) {
        const int c = i * 16 + cg;
        const float4 x = imgb[(size_t)c * N4_ + n4];
        float p = w4.x * x.x + w4.y * x.y + w4.z * x.z + w4.w * x.w;
        p += __shfl_xor(p, 1); p += __shfl_xor(p, 2);
        p += __shfl_xor(p, 4); p += __shfl_xor(p, 8);
        if (n4 == 0) Ppart[((size_t)b * NT_ + nt) * C_ + c] = p;
    }
}

// ---------------- Kernel C: combine tiles + v GEMV + o GEMV ----------------
__global__ __launch_bounds__(256) void kC_combine(
    const float* __restrict__ Ppart, const float* __restrict__ msloc,
    const float* __restrict__ v_w,   const float* __restrict__ v_b,
    const float* __restrict__ o_w,   const float* __restrict__ o_b,
    float* __restrict__ outvec)
{
    const int b = blockIdx.x, tid = threadIdx.x;
    __shared__ float p_lds[C_];
    __shared__ float e_lds[E_];
    __shared__ float scl[NT_];
    __shared__ float invD_sh;

    // wave 0: global max + denominator over the 49 tiles
    if (tid < 64) {
        const bool ok = (tid < NT_);
        const float m = ok ? msloc[(b * NT_ + tid) * 2 + 0] : -1e30f;
        float M = m;
        for (int off = 32; off; off >>= 1) M = fmaxf(M, __shfl_xor(M, off));
        const float e = ok ? expf(m - M) : 0.f;
        float d = ok ? msloc[(b * NT_ + tid) * 2 + 1] * e : 0.f;
        for (int off = 32; off; off >>= 1) d += __shfl_xor(d, off);
        if (ok) scl[tid] = e;
        if (tid == 0) invD_sh = 1.f / d;
    }
    __syncthreads();
    const float invD = invD_sh;

    for (int c = tid; c < C_; c += 256) {
        float s = 0.f;
        #pragma unroll 7
        for (int t = 0; t < NT_; ++t)
            s = fmaf(Ppart[((size_t)b * NT_ + t) * C_ + c], scl[t], s);
        p_lds[c] = s * invD;   // pooled_img[b,c]
    }
    __syncthreads();
    {   // pooled[e] = v_b[e] + v_w[e,:] . pooled_img
        const int e = tid;
        float acc = v_b[e];
        const float* vw = v_w + (size_t)e * C_;
        #pragma unroll 4
        for (int c = 0; c < C_; ++c) acc = fmaf(vw[c], p_lds[c], acc);
        e_lds[e] = acc;
    }
    __syncthreads();
    for (int c = tid; c < C_; c += 256) {
        float acc = o_b[c];
        const float* ow = o_w + (size_t)c * E_;
        #pragma unroll 4
        for (int e = 0; e < E_; ++e) acc = fmaf(ow[e], e_lds[e], acc);
        outvec[b * C_ + c] = acc;
    }
}

// ---------------- Kernel D: out = img + outvec[b,c] broadcast --------------
__global__ __launch_bounds__(256) void kD_add(
    const float* __restrict__ img, const float* __restrict__ outvec,
    float* __restrict__ out)
{
    const unsigned i = blockIdx.x * 256u + threadIdx.x;   // < TOTAL4_
    const float4 x = ((const float4*)img)[i];
    const float o = outvec[i / N4_];   // row = b*C_+c; L1/L2 broadcast
    float4 r;
    r.x = x.x + o; r.y = x.y + o; r.z = x.z + o; r.w = x.w + o;
    ((float4*)out)[i] = r;
}

extern "C" void kernel_launch(void* const* d_in, const int* in_sizes, int n_in,
                              void* d_out, int out_size, void* d_ws, size_t ws_size,
                              hipStream_t stream) {
    const float* text = (const float*)d_in[0];
    const float* img  = (const float*)d_in[1];
    const float* q_w  = (const float*)d_in[2];
    const float* q_b  = (const float*)d_in[3];
    const float* k_w  = (const float*)d_in[4];
    const float* k_b  = (const float*)d_in[5];  // unused: cancels in softmax
    const float* v_w  = (const float*)d_in[6];
    const float* v_b  = (const float*)d_in[7];
    const float* o_w  = (const float*)d_in[8];
    const float* o_b  = (const float*)d_in[9];
    float* out = (float*)d_out;
    (void)k_b; (void)in_sizes; (void)n_in; (void)out_size; (void)ws_size;

    // workspace layout (floats)
    float* ws     = (float*)d_ws;
    float* qk     = ws;                      // B_*C_        = 14336
    float* Ppart  = qk + B_ * C_;            // B_*NT_*C_    = 702464
    float* msloc  = Ppart + B_ * NT_ * C_;   // B_*NT_*2     = 3136
    float* outvec = msloc + B_ * NT_ * 2;    // B_*C_        = 14336

    kA_qk<<<B_, 256, 0, stream>>>(text, q_w, q_b, k_w, qk);
    kB_logits_pool<<<dim3(NT_, B_), 256, 0, stream>>>(img, qk, Ppart, msloc);
    kC_combine<<<B_, 256, 0, stream>>>(Ppart, msloc, v_w, v_b, o_w, o_b, outvec);
    kD_add<<<TOTAL4_ / 256, 256, 0, stream>>>(img, outvec, out);
}